// Round 5
// baseline (1990.925 us; speedup 1.0000x reference)
//
#include <hip/hip_runtime.h>

#define N_NODES 200000
#define N_EDGES 800000
#define N_RULES 50000
#define NLAYERS 24
#define SCAN_NB 196        // ceil(200000/1024)
#define RP_STRIDE 200064   // ints per rp array (padded)

typedef short bf16x8 __attribute__((ext_vector_type(8)));
typedef float floatx4 __attribute__((ext_vector_type(4)));
typedef short shortx4 __attribute__((ext_vector_type(4)));

__device__ __forceinline__ unsigned short f2bf(float f) {
  unsigned int b = __float_as_uint(f);
  b += 0x7FFFu + ((b >> 16) & 1u);          // round-to-nearest-even
  return (unsigned short)(b >> 16);
}
__device__ __forceinline__ float bf2f(unsigned short u) {
  return __uint_as_float(((unsigned int)u) << 16);
}

// ---------------- CSR build ----------------

__global__ void k_hist(const int* __restrict__ src, const int* __restrict__ tgt,
                       int* __restrict__ deg_out, int* __restrict__ deg_back) {
  int e = blockIdx.x * 256 + threadIdx.x;   // E = 3125*256 exact
  atomicAdd(&deg_out[tgt[e]], 1);
  atomicAdd(&deg_back[src[e]], 1);
}

__global__ void k_scanA(const int* __restrict__ deg, int* __restrict__ part) {
  int y = blockIdx.y;
  const int* d = deg + y * N_NODES;
  __shared__ int sh[256];
  int t = threadIdx.x;
  int base = blockIdx.x * 1024 + t * 4;
  int s = 0;
  #pragma unroll
  for (int k = 0; k < 4; ++k) { int i = base + k; if (i < N_NODES) s += d[i]; }
  sh[t] = s; __syncthreads();
  for (int off = 128; off > 0; off >>= 1) { if (t < off) sh[t] += sh[t + off]; __syncthreads(); }
  if (t == 0) part[y * SCAN_NB + blockIdx.x] = sh[0];
}

__global__ void k_scanB(int* __restrict__ part, int* __restrict__ rp) {
  int y = blockIdx.y;
  __shared__ int buf[256];
  int t = threadIdx.x;
  int v = (t < SCAN_NB) ? part[y * SCAN_NB + t] : 0;
  buf[t] = v; __syncthreads();
  for (int off = 1; off < 256; off <<= 1) {
    int x = (t >= off) ? buf[t - off] : 0;
    __syncthreads();
    buf[t] += x;
    __syncthreads();
  }
  if (t < SCAN_NB) part[y * SCAN_NB + t] = buf[t] - v;   // exclusive
  if (t == 0) rp[y * RP_STRIDE + N_NODES] = N_EDGES;
}

__global__ void k_scanC(const int* __restrict__ deg, const int* __restrict__ part,
                        int* __restrict__ rp) {
  int y = blockIdx.y;
  const int* d = deg + y * N_NODES;
  int* r = rp + y * RP_STRIDE;
  __shared__ int buf[256];
  int t = threadIdx.x;
  int base = blockIdx.x * 1024 + t * 4;
  int dv[4]; int s = 0;
  #pragma unroll
  for (int k = 0; k < 4; ++k) { int i = base + k; dv[k] = (i < N_NODES) ? d[i] : 0; s += dv[k]; }
  buf[t] = s; __syncthreads();
  int sv = s;
  for (int off = 1; off < 256; off <<= 1) {
    int x = (t >= off) ? buf[t - off] : 0;
    __syncthreads();
    buf[t] += x;
    __syncthreads();
  }
  int e = part[y * SCAN_NB + blockIdx.x] + buf[t] - sv;
  #pragma unroll
  for (int k = 0; k < 4; ++k) { int i = base + k; if (i < N_NODES) r[i] = e; e += dv[k]; }
}

__global__ void k_fill(const int* __restrict__ src, const int* __restrict__ tgt,
                       const int* __restrict__ rp_out, const int* __restrict__ rp_back,
                       int* __restrict__ cur_out, int* __restrict__ cur_back,
                       int* __restrict__ ci_out, int* __restrict__ ci_back) {
  int e = blockIdx.x * 256 + threadIdx.x;
  int s = src[e], t = tgt[e];
  int p = rp_out[t] + atomicAdd(&cur_out[t], 1);
  ci_out[p] = s;
  int q = rp_back[s] + atomicAdd(&cur_back[s], 1);
  ci_back[q] = t;
}

// ---------------- BN-folded weight prep (bf16 MFMA A-fragments) ----------------
__global__ void k_prep(const float* __restrict__ W, const float* __restrict__ b,
                       const float* __restrict__ gamma, const float* __restrict__ beta,
                       const float* __restrict__ rmean, const float* __restrict__ rvar,
                       unsigned short* __restrict__ WpF, float* __restrict__ bp) {
  int d = blockIdx.x, l = blockIdx.y, lane = threadIdx.x;
  int ld = l * 2 + d;
  __shared__ float s_s[64], t_s[64];
  float s = gamma[ld * 64 + lane] * rsqrtf(rvar[ld * 64 + lane] + 1e-5f);
  s_s[lane] = s;
  t_s[lane] = beta[ld * 64 + lane] - rmean[ld * 64 + lane] * s;
  __syncthreads();
  float bias = b[ld * 64 + lane];
  for (int j = 0; j < 64; ++j) bias += W[(ld * 64 + lane) * 64 + j] * t_s[j];
  bp[ld * 64 + lane] = bias;
  #pragma unroll
  for (int f = 0; f < 8; ++f) {
    int ct = f >> 1, kh = f & 1;
    int row = ct * 16 + (lane & 15);
    #pragma unroll
    for (int jj = 0; jj < 8; ++jj) {
      int k = kh * 32 + (lane >> 4) * 8 + jj;
      float val = W[(ld * 64 + row) * 64 + k] * s_s[k];
      WpF[(ld * 8 + f) * 512 + lane * 8 + jj] = f2bf(val);
    }
  }
}

// ---------------- Wh prep: split bf16 hi/lo MFMA A-fragments ----------------
__global__ void k_prep2(const float* __restrict__ Wh,
                        unsigned short* __restrict__ WhFhi,
                        unsigned short* __restrict__ WhFlo) {
  int jt = blockIdx.x, lane = threadIdx.x;
  #pragma unroll
  for (int kh = 0; kh < 2; ++kh) {
    #pragma unroll
    for (int jj = 0; jj < 8; ++jj) {
      int j = jt * 16 + (lane & 15);
      int k = kh * 32 + (lane >> 4) * 8 + jj;
      float wv = Wh[j * 64 + k];
      unsigned short hi = f2bf(wv);
      WhFhi[(jt * 2 + kh) * 512 + lane * 8 + jj] = hi;
      WhFlo[(jt * 2 + kh) * 512 + lane * 8 + jj] = f2bf(wv - bf2f(hi));
    }
  }
}

// ---------------- embedding gather (fp32 master + bf16 shadow) ----------------
__global__ void k_embed(const int* __restrict__ nodes, const float* __restrict__ emb,
                        float* __restrict__ x, unsigned short* __restrict__ xbf) {
  int gid = blockIdx.x * 256 + threadIdx.x;     // N*64 = 50000*256 exact
  int i = gid >> 6, c = gid & 63;
  float v = emb[nodes[i] * 64 + c];
  x[gid] = v;
  xbf[gid] = f2bf(v);
}

// ---------------- fused layer ----------------
// Software-pipelined gather-mean (bf16 shadow, both dirs) + MFMA + in-place
// residual. 1 wave = 16 nodes. No barriers; LDS only for the 16x64 m tile
// (B-fragment transpose). y kept in registers in MFMA D layout; epilogue
// reads/writes x and xbf in that layout (still 16B/lane coalesced).
__global__ __launch_bounds__(256) void k_layer(
    float* __restrict__ x,                         // fp32 master, updated in place
    const unsigned short* __restrict__ xbf_in,     // bf16 shadow (input gen)
    unsigned short* __restrict__ xbf_out,          // bf16 shadow (output gen)
    const int* __restrict__ rp0, const int* __restrict__ ci0,
    const int* __restrict__ rp1, const int* __restrict__ ci1,
    const unsigned short* __restrict__ WfL, const float* __restrict__ bpL) {
  __shared__ __align__(16) unsigned short m_s[4][16 * 72];  // bf16, pitch 72
  int tid = threadIdx.x, lane = tid & 63, w = tid >> 6;
  int base = (blockIdx.x * 4 + w) * 16;
  int n15 = lane & 15, q = lane >> 4;
  float y[16];                                    // 4 ct x 4 f32, MFMA D layout

  #pragma unroll
  for (int d = 0; d < 2; ++d) {
    const int* rp = d ? rp1 : rp0;
    const int* ci = d ? ci1 : ci0;
    // rp[base..base+16] in one coalesced load; scalars via readlane (no LDS)
    int rpv = rp[base + (lane < 17 ? lane : 16)];
    int rs = __builtin_amdgcn_readlane(rpv, 0);
    int re = __builtin_amdgcn_readlane(rpv, 16);
    int cur = 0, cstart = rs;
    int cend = __builtin_amdgcn_readlane(rpv, 1);
    float acc = 0.f;
    // edge-id chunks (64 each). Unguarded loads: overreads stay inside d_ws;
    // garbage ids are masked below and never accumulated (j<re scalar guard).
    int cv_cur = ci[rs + lane];
    int cv_nxt = ci[rs + 64 + lane];
    int nb = (re - rs + 15) >> 4;                 // scalar count of 16-edge batches
    unsigned short v0[16], v1[16];

#define ISSUE(buf, b)                                                      \
    {                                                                      \
      int bb_ = ((b) & 3) << 4;                                            \
      _Pragma("unroll")                                                    \
      for (int u = 0; u < 16; ++u) {                                       \
        int sn = __builtin_amdgcn_readlane(cv_cur, bb_ + u) & 0x3FFFF;     \
        buf[u] = xbf_in[sn * 64 + lane];                                   \
      }                                                                    \
    }
#define CONSUME(buf, b)                                                    \
    {                                                                      \
      int jb_ = rs + (b) * 16;                                             \
      _Pragma("unroll")                                                    \
      for (int u = 0; u < 16; ++u) {                                       \
        int j = jb_ + u;                                                   \
        if (j < re) {                                                      \
          while (j >= cend) {                                              \
            int deg = cend - cstart;                                       \
            float invc = deg > 0 ? 1.f / (float)deg : 0.f;                 \
            m_s[w][cur * 72 + lane] = f2bf(acc * invc);                    \
            acc = 0.f; cur++; cstart = cend;                               \
            cend = __builtin_amdgcn_readlane(rpv, cur + 1);                \
          }                                                                \
          acc += bf2f(buf[u]);                                             \
        }                                                                  \
      }                                                                    \
    }

    if (nb > 0) ISSUE(v0, 0);
    int i = 0;
    for (; i + 2 <= nb; i += 2) {
      ISSUE(v1, i + 1);                           // next batch in flight
      CONSUME(v0, i);
      if (i + 2 < nb) {
        if (((i + 2) & 3) == 0) {                 // batch i+2 starts a new chunk
          cv_cur = cv_nxt;
          cv_nxt = ci[rs + (i + 2) * 16 + 64 + lane];
        }
        ISSUE(v0, i + 2);
      }
      CONSUME(v1, i + 1);
    }
    if (i < nb) CONSUME(v0, i);                   // odd tail
#undef ISSUE
#undef CONSUME

    #pragma unroll 1
    while (cur < 16) {                            // trailing flush
      int deg = cend - cstart;
      float invc = deg > 0 ? 1.f / (float)deg : 0.f;
      m_s[w][cur * 72 + lane] = f2bf(acc * invc);
      acc = 0.f; cstart = cend; cur++;
      if (cur < 16) cend = __builtin_amdgcn_readlane(rpv, cur + 1);
    }

    // MFMA: y[64ch x 16node] = W' @ m ; per-wave LDS, no barrier needed
    const unsigned short* wf = WfL + d * 4096;
    bf16x8 b0 = *(const bf16x8*)&m_s[w][n15 * 72 + q * 8];
    bf16x8 b1 = *(const bf16x8*)&m_s[w][n15 * 72 + 32 + q * 8];
    #pragma unroll
    for (int ct = 0; ct < 4; ++ct) {
      floatx4 d4 = {0.f, 0.f, 0.f, 0.f};
      bf16x8 a0 = *(const bf16x8*)(wf + (ct * 2 + 0) * 512 + lane * 8);
      bf16x8 a1 = *(const bf16x8*)(wf + (ct * 2 + 1) * 512 + lane * 8);
      d4 = __builtin_amdgcn_mfma_f32_16x16x32_bf16(a0, b0, d4, 0, 0, 0);
      d4 = __builtin_amdgcn_mfma_f32_16x16x32_bf16(a1, b1, d4, 0, 0, 0);
      // D: col = n15 = node, row = ct*16 + q*4 + i = channel
      floatx4 bp4 = *(const floatx4*)(bpL + d * 64 + ct * 16 + q * 4);
      #pragma unroll
      for (int i2 = 0; i2 < 4; ++i2) {
        float yv = fmaxf(d4[i2] + bp4[i2], 0.f);
        if (d == 0) y[ct * 4 + i2] = yv; else y[ct * 4 + i2] += yv;
      }
    }
  }

  // epilogue in MFMA D layout: lane (n15,q) owns ch [ct*16+q*4, +4) of node n15
  int nrow = base + n15;
  #pragma unroll
  for (int ct = 0; ct < 4; ++ct) {
    float* xp = &x[nrow * 64 + ct * 16 + q * 4];
    floatx4 xo = *(const floatx4*)xp;
    #pragma unroll
    for (int i2 = 0; i2 < 4; ++i2) xo[i2] += y[ct * 4 + i2];
    *(floatx4*)xp = xo;
    shortx4 hb;
    #pragma unroll
    for (int i2 = 0; i2 < 4; ++i2) hb[i2] = (short)f2bf(xo[i2]);
    *(shortx4*)&xbf_out[nrow * 64 + ct * 16 + q * 4] = hb;
  }
}

// ---------------- readout (MFMA, split-bf16 Wh AND split-bf16 x) ----------------
__global__ __launch_bounds__(256) void k_final(
    const float* __restrict__ x, const int* __restrict__ rules,
    const unsigned short* __restrict__ WhFhi, const unsigned short* __restrict__ WhFlo,
    const float* __restrict__ bh, const float* __restrict__ Wo,
    float* __restrict__ out) {
  __shared__ __align__(16) float bh_s[1024], wo_s[1024];
  int tid = threadIdx.x, lane = tid & 63, w = tid >> 6;
  ((floatx4*)bh_s)[tid] = ((const floatx4*)bh)[tid];
  ((floatx4*)wo_s)[tid] = ((const floatx4*)Wo)[tid];
  __syncthreads();
  int n15 = lane & 15, q = lane >> 4;
  int rbase = (blockIdx.x * 4 + w) * 16;
  int ru = rbase + n15;
  int nd = rules[ru < N_RULES ? ru : N_RULES - 1];
  const float* xr = x + nd * 64;
  floatx4 xa = *(const floatx4*)&xr[q * 8];
  floatx4 xb = *(const floatx4*)&xr[q * 8 + 4];
  floatx4 xc = *(const floatx4*)&xr[32 + q * 8];
  floatx4 xd = *(const floatx4*)&xr[32 + q * 8 + 4];
  bf16x8 b0h, b0l, b1h, b1l;
  #pragma unroll
  for (int i = 0; i < 4; ++i) {
    unsigned short h;
    h = f2bf(xa[i]); b0h[i]     = (short)h; b0l[i]     = (short)f2bf(xa[i] - bf2f(h));
    h = f2bf(xb[i]); b0h[4 + i] = (short)h; b0l[4 + i] = (short)f2bf(xb[i] - bf2f(h));
    h = f2bf(xc[i]); b1h[i]     = (short)h; b1l[i]     = (short)f2bf(xc[i] - bf2f(h));
    h = f2bf(xd[i]); b1h[4 + i] = (short)h; b1l[4 + i] = (short)f2bf(xd[i] - bf2f(h));
  }
  float acc = 0.f;
  #pragma unroll 4
  for (int jt = 0; jt < 64; ++jt) {
    const unsigned short* fh = WhFhi + (jt * 2) * 512 + lane * 8;
    const unsigned short* fl = WhFlo + (jt * 2) * 512 + lane * 8;
    bf16x8 a0h = *(const bf16x8*)fh;
    bf16x8 a1h = *(const bf16x8*)(fh + 512);
    bf16x8 a0l = *(const bf16x8*)fl;
    bf16x8 a1l = *(const bf16x8*)(fl + 512);
    floatx4 d4 = {0.f, 0.f, 0.f, 0.f};
    d4 = __builtin_amdgcn_mfma_f32_16x16x32_bf16(a0h, b0h, d4, 0, 0, 0);
    d4 = __builtin_amdgcn_mfma_f32_16x16x32_bf16(a1h, b1h, d4, 0, 0, 0);
    d4 = __builtin_amdgcn_mfma_f32_16x16x32_bf16(a0h, b0l, d4, 0, 0, 0);
    d4 = __builtin_amdgcn_mfma_f32_16x16x32_bf16(a1h, b1l, d4, 0, 0, 0);
    d4 = __builtin_amdgcn_mfma_f32_16x16x32_bf16(a0l, b0h, d4, 0, 0, 0);
    d4 = __builtin_amdgcn_mfma_f32_16x16x32_bf16(a1l, b1h, d4, 0, 0, 0);
    floatx4 bh4 = *(const floatx4*)&bh_s[jt * 16 + q * 4];
    floatx4 wo4 = *(const floatx4*)&wo_s[jt * 16 + q * 4];
    #pragma unroll
    for (int i = 0; i < 4; ++i)
      acc += fmaxf(d4[i] + bh4[i], 0.f) * wo4[i];
  }
  acc += __shfl_down(acc, 32);     // fold q2,q3 into q0,q1
  acc += __shfl_down(acc, 16);     // fold q1 into q0
  if (lane < 16 && rbase + lane < N_RULES) out[rbase + lane] = acc;
}

// ---------------- launch ----------------
extern "C" void kernel_launch(void* const* d_in, const int* in_sizes, int n_in,
                              void* d_out, int out_size, void* d_ws, size_t ws_size,
                              hipStream_t stream) {
  const int* nodes = (const int*)d_in[0];
  const int* sources = (const int*)d_in[1];
  const int* targets = (const int*)d_in[2];
  const int* rules = (const int*)d_in[3];
  const float* emb = (const float*)d_in[4];
  const float* W = (const float*)d_in[5];
  const float* b = (const float*)d_in[6];
  const float* gamma = (const float*)d_in[7];
  const float* beta = (const float*)d_in[8];
  const float* rmean = (const float*)d_in[9];
  const float* rvar = (const float*)d_in[10];
  const float* Wh = (const float*)d_in[11];
  const float* bh = (const float*)d_in[12];
  const float* Wo = (const float*)d_in[13];
  float* out = (float*)d_out;

  if (ws_size < 114270000u) return;  // need ~114.3 MB scratch

  char* ws = (char*)d_ws;
  float* x = (float*)(ws + 0);                              // 51.2 MB fp32 master
  unsigned short* xbf_a = (unsigned short*)(ws + 51200000); // 25.6 MB bf16 shadow
  unsigned short* xbf_b = (unsigned short*)(ws + 76800000); // 25.6 MB bf16 shadow
  int* deg_out = (int*)(ws + 102400000);                    // 800 KB
  int* deg_back = deg_out + N_NODES;                        // 800 KB
  int* cur_out = (int*)(ws + 104000000);                    // 800 KB
  int* cur_back = (int*)(ws + 104800000);                   // 800 KB
  int* rp_out = (int*)(ws + 105600000);                     // 2 x RP_STRIDE ints
  int* rp_back = rp_out + RP_STRIDE;
  int* ci_out = (int*)(ws + 107200512);                     // 3.2 MB
  int* ci_back = (int*)(ws + 110400512);                    // 3.2 MB
  int* part = (int*)(ws + 113600512);                       // 1568 B
  unsigned short* WpF = (unsigned short*)(ws + 113602096);  // 384 KB (16B aligned)
  float* bp = (float*)(ws + 113995312);                     // 12 KB -> ends 114007600
  unsigned short* WhFhi = (unsigned short*)(ws + 114007600); // 128 KB
  unsigned short* WhFlo = (unsigned short*)(ws + 114138672); // 128 KB -> ends 114269744

  // zero deg_out/deg_back/cur_out/cur_back (contiguous 3.2 MB)
  hipMemsetAsync(deg_out, 0, 3200000u, stream);

  k_hist<<<3125, 256, 0, stream>>>(sources, targets, deg_out, deg_back);
  k_scanA<<<dim3(SCAN_NB, 2), 256, 0, stream>>>(deg_out, part);
  k_scanB<<<dim3(1, 2), 256, 0, stream>>>(part, rp_out);
  k_scanC<<<dim3(SCAN_NB, 2), 256, 0, stream>>>(deg_out, part, rp_out);
  k_fill<<<3125, 256, 0, stream>>>(sources, targets, rp_out, rp_back,
                                   cur_out, cur_back, ci_out, ci_back);
  k_prep<<<dim3(2, NLAYERS), 64, 0, stream>>>(W, b, gamma, beta, rmean, rvar, WpF, bp);
  k_prep2<<<64, 64, 0, stream>>>(Wh, WhFhi, WhFlo);
  k_embed<<<50000, 256, 0, stream>>>(nodes, emb, x, xbf_a);

  const unsigned short* bi = xbf_a;
  unsigned short* bo = xbf_b;
  for (int l = 0; l < NLAYERS; ++l) {
    k_layer<<<3125, 256, 0, stream>>>(x, bi, bo, rp_out, ci_out, rp_back, ci_back,
                                      WpF + (size_t)l * 8192, bp + (size_t)l * 128);
    const unsigned short* t = bi; bi = bo; bo = (unsigned short*)t;
  }
  k_final<<<782, 256, 0, stream>>>(x, rules, WhFhi, WhFlo, bh, Wo, out);
}